// Round 1
// 1107.295 us; speedup vs baseline: 1.1746x; 1.1746x over previous
//
#include <hip/hip_runtime.h>
#include <math.h>

#define N_GRAPHS 512
#define N_PER    1024
#define NN       (N_GRAPHS * N_PER)   // 524288 nodes
#define NE       4194304              // edges
#define DF       256                  // feature dim
#define KK       512                  // keep per graph
#define GK       (N_GRAPHS * KK)      // 262144 output rows

// Packed-accumulator layout (one u64 atomic per edge):
//   bits [63:50] : count of non-self edges landing on this row (max 16383)
//   bits [49: 0] : sum of (term + 32.0) in fixed-point, scale 2^30
// Each per-edge addend is >= 0 (term clamped to [-32,32]), so the low field
// accumulates monotonically and can never borrow into the count field.
// Integer adds are exactly associative -> result is order-independent.
#define FIX_SCALE 1073741824.0        // 2^30
#define BIAS_F    32.0f
#define BIAS_FIX  (1ll << 35)         // 32 * 2^30
#define CNT_SHIFT 50
#define LOW_MASK  ((1ull << CNT_SHIFT) - 1)

// ---------------- init: acc=0 (u64), selfcnt=0 ----------------
__global__ void k_init(unsigned long long* __restrict__ acc,
                       unsigned int* __restrict__ selfcnt) {
    int i = blockIdx.x * blockDim.x + threadIdx.x;
    if (i < NN) { acc[i] = 0ull; selfcnt[i] = 0u; }
}

// ---------------- support = X @ W  (one wave per row) ----------------
__global__ void k_support(const float* __restrict__ X, const float* __restrict__ W,
                          float* __restrict__ support) {
    __shared__ float sW[DF];
    int t = threadIdx.x;          // 256 threads
    sW[t] = W[t];
    __syncthreads();
    int wv = t >> 6, lane = t & 63;
    int row = blockIdx.x * 4 + wv;              // grid = NN/4
    const float4 x = ((const float4*)(X + (size_t)row * DF))[lane];
    const float4 w = ((const float4*)sW)[lane];
    float s = x.x * w.x + x.y * w.y + x.z * w.z + x.w * w.w;
    #pragma unroll
    for (int off = 32; off; off >>= 1) s += __shfl_down(s, off, 64);
    if (lane == 0) support[row] = s;
}

// ---------------- edge scatter: ONE packed u64 atomic per edge ----------
__global__ void k_scatter(const int* __restrict__ row, const int* __restrict__ col,
                          const float* __restrict__ adj, const float* __restrict__ support,
                          unsigned long long* __restrict__ acc,
                          unsigned int* __restrict__ selfcnt) {
    int e = blockIdx.x * blockDim.x + threadIdx.x;
    if (e >= NE) return;
    int r = row[e], c = col[e];
    float term = adj[e] * support[c];            // fp32 term like reference
    term = fminf(fmaxf(term, -BIAS_F), BIAS_F);  // never active for this data
    long long f = llrint((double)term * FIX_SCALE);   // exact fixed-point
    unsigned long long contrib =
        ((unsigned long long)(r != c) << CNT_SHIFT) +
        (unsigned long long)(f + BIAS_FIX);
    atomicAdd(&acc[r], contrib);
    if (r == c) atomicAdd(&selfcnt[r], 1u);      // ~8 times total over 4M edges
}

// ---- decode: attn = tanh(sum); diag = 1/deg; rs = rsqrt(deg) (in-place) ----
__global__ void k_finalize(const unsigned long long* __restrict__ acc,
                           unsigned int* __restrict__ self_then_rs,
                           float* __restrict__ attn, float* __restrict__ diag) {
    int i = blockIdx.x * blockDim.x + threadIdx.x;
    if (i >= NN) return;
    unsigned long long a = acc[i];
    unsigned int cnt = (unsigned int)(a >> CNT_SHIFT);      // non-self edges
    unsigned long long low = a & LOW_MASK;
    unsigned int selfc = self_then_rs[i];                   // read BEFORE overwrite
    long long sfix = (long long)low
                   - ((long long)(cnt + selfc) << 35);      // remove per-edge bias
    float sum = (float)((double)sfix * (1.0 / FIX_SCALE));
    attn[i] = tanhf(sum);
    float degf = (float)(1u + cnt);
    diag[i] = 1.0f / degf;
    ((float*)self_then_rs)[i] = rsqrtf(degf);               // rs for k_edgenorm
}

// ---------------- per-graph top-k via full bitonic sort in LDS ----------------
// jax.lax.top_k order: descending value; ties -> smaller index first.
__global__ void k_topk(const float* __restrict__ attn, int* __restrict__ nidx) {
    __shared__ float sv[N_PER];
    __shared__ int   si[N_PER];
    int g = blockIdx.x, t = threadIdx.x;   // 1024 threads
    int base = g * N_PER;
    sv[t] = attn[base + t];
    si[t] = t;
    __syncthreads();
    for (int k = 2; k <= N_PER; k <<= 1) {
        for (int j = k >> 1; j > 0; j >>= 1) {
            int l = t ^ j;
            if (l > t) {
                float v1 = sv[t], v2 = sv[l];
                int   i1 = si[t], i2 = si[l];
                // cmp_l_t: element l should come before element t in final order
                bool cmp_l_t = (v2 > v1) || (v2 == v1 && i2 < i1);
                bool swap = ((t & k) == 0) ? cmp_l_t : !cmp_l_t;
                if (swap) { sv[t] = v2; si[t] = i2; sv[l] = v1; si[l] = i1; }
            }
            __syncthreads();
        }
    }
    if (t < KK) nidx[g * KK + t] = base + si[t];
}

// ---------------- hidden = X[node]*attn[node]; mask = graph_indicator[node] ---
__global__ void k_gather(const float* __restrict__ X, const float* __restrict__ attn,
                         const int* __restrict__ nidx, const int* __restrict__ gi,
                         float* __restrict__ hidden, float* __restrict__ mask) {
    int t = threadIdx.x;          // 256 threads
    int wv = t >> 6, lane = t & 63;
    int r = blockIdx.x * 4 + wv;                // grid = GK/4
    int node = nidx[r];
    float a = attn[node];
    float4 x = ((const float4*)(X + (size_t)node * DF))[lane];
    x.x *= a; x.y *= a; x.z *= a; x.w *= a;
    ((float4*)(hidden + (size_t)r * DF))[lane] = x;
    if (lane == 0) mask[r] = (float)gi[node];
}

// ---------------- edge_norm = nonself * rs[r] * rs[c] --------
__global__ void k_edgenorm(const int* __restrict__ row, const int* __restrict__ col,
                           const float* __restrict__ rs, float* __restrict__ en) {
    int e = blockIdx.x * blockDim.x + threadIdx.x;
    if (e >= NE) return;
    int r = row[e], c = col[e];
    en[e] = (r != c) ? rs[r] * rs[c] : 0.0f;
}

extern "C" void kernel_launch(void* const* d_in, const int* in_sizes, int n_in,
                              void* d_out, int out_size, void* d_ws, size_t ws_size,
                              hipStream_t stream) {
    const int*   edge_index = (const int*)d_in[0];     // [2, NE]
    const float* adj_vals   = (const float*)d_in[1];   // [NE]
    const float* X          = (const float*)d_in[2];   // [NN, DF]
    const float* W          = (const float*)d_in[3];   // [DF]
    const int*   gi         = (const int*)d_in[4];     // [NN]

    const int* row = edge_index;
    const int* col = edge_index + NE;

    // outputs, concatenated flat fp32
    float* out_hidden = (float*)d_out;                       // GK*DF
    float* out_mask   = out_hidden + (size_t)GK * DF;        // GK
    float* out_edge   = out_mask + GK;                       // NE
    float* out_diag   = out_edge + NE;                       // NN

    // workspace layout (11 MB total, unchanged footprint)
    char* ws = (char*)d_ws;
    float*              support = (float*)ws;                                  // 2 MB
    unsigned long long* acc     = (unsigned long long*)(ws + (size_t)2 * 1024 * 1024); // 4 MB
    unsigned int*       selfrs  = (unsigned int*)(ws + (size_t)6 * 1024 * 1024);       // 2 MB (selfcnt, then rs)
    float*              attn    = (float*)(ws + (size_t)8 * 1024 * 1024);              // 2 MB
    int*                nidx    = (int*)(ws + (size_t)10 * 1024 * 1024);               // 1 MB

    k_init<<<NN / 256, 256, 0, stream>>>(acc, selfrs);
    k_support<<<NN / 4, 256, 0, stream>>>(X, W, support);
    k_scatter<<<NE / 256, 256, 0, stream>>>(row, col, adj_vals, support, acc, selfrs);
    k_finalize<<<NN / 256, 256, 0, stream>>>(acc, selfrs, attn, out_diag);
    k_topk<<<N_GRAPHS, N_PER, 0, stream>>>(attn, nidx);
    k_gather<<<GK / 4, 256, 0, stream>>>(X, attn, nidx, gi, out_hidden, out_mask);
    k_edgenorm<<<NE / 256, 256, 0, stream>>>(row, col, (const float*)selfrs, out_edge);
}

// Round 3
// 988.248 us; speedup vs baseline: 1.3161x; 1.1205x over previous
//
#include <hip/hip_runtime.h>
#include <math.h>

#define N_GRAPHS 512
#define N_PER    1024
#define NN       (N_GRAPHS * N_PER)   // 524288 nodes
#define NE       4194304              // edges
#define DF       256                  // feature dim
#define KK       512                  // keep per graph
#define GK       (N_GRAPHS * KK)      // 262144 output rows

// Packed-accumulator layout:
//   bits [63:50] : count of non-self edges landing on this row
//   bits [49: 0] : sum of (term + 32.0) in fixed-point, scale 2^30
// Each per-edge addend is >= 0 (term clamped to [-32,32]) -> low field is
// monotone, never borrows into the count field. Integer adds are exactly
// associative -> result is order-independent and bit-deterministic.
#define FIX_SCALE 1073741824.0        // 2^30
#define BIAS_F    32.0f
#define BIAS_FIX  (1ll << 35)         // 32 * 2^30
#define CNT_SHIFT 50
#define LOW_MASK  ((1ull << CNT_SHIFT) - 1)

// Binned-scatter geometry
#define NB   512                      // buckets = node >> 10 (one per graph)
#define B1   512                      // pass-1 blocks
#define T1   512                      // pass-1 threads
#define CHUNK (NE / B1)               // 8192 edges per pass-1 block
#define BCAP 64                       // record capacity per (bucket, block) cell
                                      // Poisson(16) tail at 64: ~1e-50 -> safe

// ---------------- init: acc=0 (u64), selfcnt=0 ----------------
__global__ void k_init(unsigned long long* __restrict__ acc,
                       unsigned int* __restrict__ selfcnt) {
    int i = blockIdx.x * blockDim.x + threadIdx.x;
    if (i < NN) { acc[i] = 0ull; selfcnt[i] = 0u; }
}

// ---------------- support = X @ W  (one wave per row) ----------------
__global__ void k_support(const float* __restrict__ X, const float* __restrict__ W,
                          float* __restrict__ support) {
    __shared__ float sW[DF];
    int t = threadIdx.x;          // 256 threads
    sW[t] = W[t];
    __syncthreads();
    int wv = t >> 6, lane = t & 63;
    int row = blockIdx.x * 4 + wv;              // grid = NN/4
    const float4 x = ((const float4*)(X + (size_t)row * DF))[lane];
    const float4 w = ((const float4*)sW)[lane];
    float s = x.x * w.x + x.y * w.y + x.z * w.z + x.w * w.w;
    #pragma unroll
    for (int off = 32; off; off >>= 1) s += __shfl_down(s, off, 64);
    if (lane == 0) support[row] = s;
}

// ============ PASS 1: bin edges by destination bucket (no global atomics) ====
// record: .x = row | (nonself<<31), .y = bit pattern of fp32 term
__global__ void k_bin(const int* __restrict__ row, const int* __restrict__ col,
                      const float* __restrict__ adj, const float* __restrict__ support,
                      uint2* __restrict__ recs, unsigned int* __restrict__ cnts,
                      unsigned int* __restrict__ selfcnt) {
    __shared__ uint2        rec[CHUNK];     // 64 KB
    __shared__ unsigned int cnt[NB];        // per-bucket count (this block)
    __shared__ unsigned int ls[NB];         // exclusive scan (local start)
    __shared__ unsigned int cur[NB];        // placement cursor
    int t = threadIdx.x;                    // T1 = 512
    int blk = blockIdx.x;
    int base = blk * CHUNK;

    cnt[t] = 0u;
    __syncthreads();

    // count
    #pragma unroll
    for (int k = 0; k < CHUNK / T1; ++k) {
        int r = row[base + k * T1 + t];
        atomicAdd(&cnt[r >> 10], 1u);
    }
    __syncthreads();

    // inclusive scan (Hillis-Steele over NB=512, one bucket per thread)
    ls[t] = cnt[t];
    __syncthreads();
    for (int off = 1; off < NB; off <<= 1) {
        unsigned int add = (t >= off) ? ls[t - off] : 0u;
        __syncthreads();
        ls[t] += add;
        __syncthreads();
    }
    ls[t] -= cnt[t];                 // exclusive
    cur[t] = ls[t];
    // per-(bucket,block) counts out (bucket-major for coalesced pass-2 reads)
    cnts[(size_t)t * B1 + blk] = cnt[t];
    __syncthreads();

    // place records into LDS grouped by bucket
    #pragma unroll
    for (int k = 0; k < CHUNK / T1; ++k) {
        int e = base + k * T1 + t;
        int r = row[e], c = col[e];
        float term = adj[e] * support[c];      // fp32 term like reference
        unsigned int ns = (r != c) ? 1u : 0u;
        if (!ns) atomicAdd(&selfcnt[r], 1u);   // ~8 times total over 4M edges
        unsigned int pos = atomicAdd(&cur[r >> 10], 1u);
        rec[pos] = make_uint2((unsigned int)r | (ns << 31), __float_as_uint(term));
    }
    __syncthreads();

    // copy out, bucket-grouped -> mostly-contiguous streaming writes
    for (int j = t; j < CHUNK; j += T1) {
        uint2 u = rec[j];
        unsigned int b = (u.x & 0x7FFFFFFFu) >> 10;
        unsigned int local = j - ls[b];
        if (local < BCAP)                      // defensive; never trips
            recs[((size_t)b * B1 + blk) * BCAP + local] = u;
    }
}

// ============ PASS 2: accumulate one bucket per block via LDS u64 atomics ====
__global__ void k_accum(const uint2* __restrict__ recs,
                        const unsigned int* __restrict__ cnts,
                        unsigned long long* __restrict__ acc) {
    __shared__ unsigned long long lacc[N_PER];   // 8 KB
    int t = threadIdx.x;                         // 256 threads
    int b = blockIdx.x;                          // NB blocks
    #pragma unroll
    for (int k = 0; k < N_PER / 256; ++k) lacc[t + k * 256] = 0ull;
    __syncthreads();

    for (int blk = t; blk < B1; blk += 256) {
        unsigned int n = cnts[(size_t)b * B1 + blk];
        if (n > BCAP) n = BCAP;
        const uint2* p = recs + ((size_t)b * B1 + blk) * BCAP;
        for (unsigned int i = 0; i < n; ++i) {
            uint2 u = p[i];
            unsigned int lr = u.x & (N_PER - 1);
            unsigned long long ns = (unsigned long long)(u.x >> 31);
            float term = __uint_as_float(u.y);
            term = fminf(fmaxf(term, -BIAS_F), BIAS_F);
            long long f = llrint((double)term * FIX_SCALE);
            atomicAdd(&lacc[lr], (ns << CNT_SHIFT) + (unsigned long long)(f + BIAS_FIX));
        }
    }
    __syncthreads();
    #pragma unroll
    for (int k = 0; k < N_PER / 256; ++k)
        acc[(size_t)b * N_PER + t + k * 256] = lacc[t + k * 256];
}

// ---------------- fallback: direct atomic scatter (if workspace too small) ---
__global__ void k_scatter(const int* __restrict__ row, const int* __restrict__ col,
                          const float* __restrict__ adj, const float* __restrict__ support,
                          unsigned long long* __restrict__ acc,
                          unsigned int* __restrict__ selfcnt) {
    int e = blockIdx.x * blockDim.x + threadIdx.x;
    if (e >= NE) return;
    int r = row[e], c = col[e];
    float term = adj[e] * support[c];
    term = fminf(fmaxf(term, -BIAS_F), BIAS_F);
    long long f = llrint((double)term * FIX_SCALE);
    unsigned long long contrib =
        ((unsigned long long)(r != c) << CNT_SHIFT) +
        (unsigned long long)(f + BIAS_FIX);
    atomicAdd(&acc[r], contrib);
    if (r == c) atomicAdd(&selfcnt[r], 1u);
}

// ---- decode: attn = tanh(sum); diag = 1/deg; rs = rsqrt(deg) (in-place) ----
__global__ void k_finalize(const unsigned long long* __restrict__ acc,
                           unsigned int* __restrict__ self_then_rs,
                           float* __restrict__ attn, float* __restrict__ diag) {
    int i = blockIdx.x * blockDim.x + threadIdx.x;
    if (i >= NN) return;
    unsigned long long a = acc[i];
    unsigned int cnt = (unsigned int)(a >> CNT_SHIFT);      // non-self edges
    unsigned long long low = a & LOW_MASK;
    unsigned int selfc = self_then_rs[i];                   // read BEFORE overwrite
    long long sfix = (long long)low
                   - ((long long)(cnt + selfc) << 35);      // remove per-edge bias
    float sum = (float)((double)sfix * (1.0 / FIX_SCALE));
    attn[i] = tanhf(sum);
    float degf = (float)(1u + cnt);
    diag[i] = 1.0f / degf;
    ((float*)self_then_rs)[i] = rsqrtf(degf);               // rs for k_edgenorm
}

// ---------------- per-graph top-k via full bitonic sort in LDS ----------------
// jax.lax.top_k order: descending value; ties -> smaller index first.
__global__ void k_topk(const float* __restrict__ attn, int* __restrict__ nidx) {
    __shared__ float sv[N_PER];
    __shared__ int   si[N_PER];
    int g = blockIdx.x, t = threadIdx.x;   // 1024 threads
    int base = g * N_PER;
    sv[t] = attn[base + t];
    si[t] = t;
    __syncthreads();
    for (int k = 2; k <= N_PER; k <<= 1) {
        for (int j = k >> 1; j > 0; j >>= 1) {
            int l = t ^ j;
            if (l > t) {
                float v1 = sv[t], v2 = sv[l];
                int   i1 = si[t], i2 = si[l];
                bool cmp_l_t = (v2 > v1) || (v2 == v1 && i2 < i1);
                bool swap = ((t & k) == 0) ? cmp_l_t : !cmp_l_t;
                if (swap) { sv[t] = v2; si[t] = i2; sv[l] = v1; si[l] = i1; }
            }
            __syncthreads();
        }
    }
    if (t < KK) nidx[g * KK + t] = base + si[t];
}

// ---------------- hidden = X[node]*attn[node]; mask = graph_indicator[node] ---
__global__ void k_gather(const float* __restrict__ X, const float* __restrict__ attn,
                         const int* __restrict__ nidx, const int* __restrict__ gi,
                         float* __restrict__ hidden, float* __restrict__ mask) {
    int t = threadIdx.x;          // 256 threads
    int wv = t >> 6, lane = t & 63;
    int r = blockIdx.x * 4 + wv;                // grid = GK/4
    int node = nidx[r];
    float a = attn[node];
    float4 x = ((const float4*)(X + (size_t)node * DF))[lane];
    x.x *= a; x.y *= a; x.z *= a; x.w *= a;
    ((float4*)(hidden + (size_t)r * DF))[lane] = x;
    if (lane == 0) mask[r] = (float)gi[node];
}

// ---------------- edge_norm = nonself * rs[r] * rs[c] --------
__global__ void k_edgenorm(const int* __restrict__ row, const int* __restrict__ col,
                           const float* __restrict__ rs, float* __restrict__ en) {
    int e = blockIdx.x * blockDim.x + threadIdx.x;
    if (e >= NE) return;
    int r = row[e], c = col[e];
    en[e] = (r != c) ? rs[r] * rs[c] : 0.0f;
}

extern "C" void kernel_launch(void* const* d_in, const int* in_sizes, int n_in,
                              void* d_out, int out_size, void* d_ws, size_t ws_size,
                              hipStream_t stream) {
    const int*   edge_index = (const int*)d_in[0];     // [2, NE]
    const float* adj_vals   = (const float*)d_in[1];   // [NE]
    const float* X          = (const float*)d_in[2];   // [NN, DF]
    const float* W          = (const float*)d_in[3];   // [DF]
    const int*   gi         = (const int*)d_in[4];     // [NN]

    const int* row = edge_index;
    const int* col = edge_index + NE;

    // outputs, concatenated flat fp32
    float* out_hidden = (float*)d_out;                       // GK*DF
    float* out_mask   = out_hidden + (size_t)GK * DF;        // GK
    float* out_edge   = out_mask + GK;                       // NE
    float* out_diag   = out_edge + NE;                       // NN

    // workspace layout
    const size_t MB = 1024 * 1024;
    char* ws = (char*)d_ws;
    float*              support = (float*)ws;                            // 2 MB @ 0
    unsigned int*       selfrs  = (unsigned int*)(ws + 2 * MB);          // 2 MB @ 2
    float*              attn    = (float*)(ws + 4 * MB);                 // 2 MB @ 4
    int*                nidx    = (int*)(ws + 6 * MB);                   // 1 MB @ 6
    unsigned int*       cnts    = (unsigned int*)(ws + 7 * MB);          // 1 MB @ 7
    unsigned long long* acc     = (unsigned long long*)(ws + 8 * MB);    // 4 MB @ 8
    uint2*              recs    = (uint2*)(ws + 12 * MB);                // 128 MB @ 12
    const size_t need = 12 * MB + (size_t)NB * B1 * BCAP * sizeof(uint2);

    k_init<<<NN / 256, 256, 0, stream>>>(acc, selfrs);
    k_support<<<NN / 4, 256, 0, stream>>>(X, W, support);
    if (ws_size >= need) {
        k_bin<<<B1, T1, 0, stream>>>(row, col, adj_vals, support, recs, cnts, selfrs);
        k_accum<<<NB, 256, 0, stream>>>(recs, cnts, acc);
    } else {
        k_scatter<<<NE / 256, 256, 0, stream>>>(row, col, adj_vals, support, acc, selfrs);
    }
    k_finalize<<<NN / 256, 256, 0, stream>>>(acc, selfrs, attn, out_diag);
    k_topk<<<N_GRAPHS, N_PER, 0, stream>>>(attn, nidx);
    k_gather<<<GK / 4, 256, 0, stream>>>(X, attn, nidx, gi, out_hidden, out_mask);
    k_edgenorm<<<NE / 256, 256, 0, stream>>>(row, col, (const float*)selfrs, out_edge);
}